// Round 2
// baseline (156872.400 us; speedup 1.0000x reference)
//
#include <hip/hip_runtime.h>
#include <math.h>

#define B_ 32
#define T_ 512
#define D_ 1024
#define H_ 1024
#define L_ 4
#define NTICK (T_ + L_ - 1)   // 515
#define RP 17                 // reduce-buffer row pad (floats), coprime with 32 banks
#define SMEM_FLOATS (512 * RP) // 8704 floats = 34816 B; aliases staging tile xs[32][256]

__device__ __forceinline__ bool waitFlag(const unsigned int* p, unsigned int target) {
    int c = 0;
    while (__hip_atomic_load(p, __ATOMIC_ACQUIRE, __HIP_MEMORY_SCOPE_AGENT) < target) {
        __builtin_amdgcn_s_sleep(2);
        if (++c > 2000000) return false;   // ~safety valve: no infinite hang
    }
    return true;
}

// Persistent kernel. 256 blocks (1/CU), 512 threads. Block = (layer, 16-col slice).
// Each thread pins 64 weight floats in VGPRs: col j, k-window = per-tile 8 consecutive
// k at offset kslot*8 within each of 8 k-tiles of the combined K=2048 (W_in ++ W_h).
// Per tick (global lockstep via count[tick]): stage x/h k-tiles in LDS, rank-update
// acc[32 batch rows], two-phase LDS k-reduction, tanh + tau update, agent store.
__global__ __launch_bounds__(512) void lnn_persist(
    const float* __restrict__ x,      // [B][T][D]
    const float* __restrict__ W_in,   // [L][D][H]
    const float* __restrict__ b_in,   // [L][H]
    const float* __restrict__ W_h,    // [L][H][H]
    const float* __restrict__ b_h,    // [L][H]
    const float* __restrict__ tau,    // [L][H]
    float* __restrict__ buf0,         // [L][B][H] state, tick-parity 0
    float* __restrict__ buf1,         // [L][B][H] state, tick-parity 1
    unsigned int* __restrict__ count) // [NTICK] lockstep counters (zeroed per launch)
{
    const int tid   = threadIdx.x;
    const int layer = blockIdx.x >> 6;
    const int jbase = (blockIdx.x & 63) << 4;
    const int jj    = tid & 15;       // col within slice
    const int kslot = tid >> 4;       // 0..31
    const int jg    = jbase + jj;

    __shared__ __align__(16) float smem[SMEM_FLOATS];
    float (*xs)[256] = (float(*)[256])smem;

    // ---- pin weights in registers (64 floats/thread), loaded once ----
    const float* Wl_in = W_in + (size_t)layer * D_ * H_;
    const float* Wl_h  = W_h  + (size_t)layer * H_ * H_;
    float w[8][8];
#pragma unroll
    for (int tl = 0; tl < 8; ++tl) {
#pragma unroll
        for (int i = 0; i < 8; ++i) {
            const int k = tl * 256 + kslot * 8 + i;
            w[tl][i] = (tl < 4) ? Wl_in[(size_t)k * H_ + jg]
                                : Wl_h[(size_t)(k - 1024) * H_ + jg];
        }
    }

    // epilogue per-col constants (thread role in reduce phases uses same jj -> same jg)
    const float bias = b_in[layer * H_ + jg] + b_h[layer * H_ + jg];
    const float tv   = tau[layer * H_ + jg];

    bool dead = false;   // only thread 0 uses

    for (int tick = 0; tick < NTICK; ++tick) {
        if (tid == 0 && tick > 0 && !dead)
            dead = !waitFlag(&count[tick - 1], 256u);
        __syncthreads();   // all threads ordered after the acquire

        const int t = tick - layer;
        if (t >= 0 && t < T_) {
            const float* rb = (tick & 1) ? buf0 : buf1;   // state at t-1
            float*       wb = (tick & 1) ? buf1 : buf0;   // state at t

            const float* xsrc; size_t xstr;
            if (layer == 0) { xsrc = x + (size_t)t * D_;               xstr = (size_t)T_ * D_; }
            else            { xsrc = rb + (size_t)(layer - 1) * B_ * H_; xstr = H_; }
            const float* hsrc = rb + (size_t)layer * B_ * H_;

            float acc[32];
#pragma unroll
            for (int i = 0; i < 32; ++i) acc[i] = 0.f;

            const int kb = kslot << 3;
#pragma unroll
            for (int tile = 0; tile < 8; ++tile) {
                const float* src = (tile < 4) ? xsrc : hsrc;
                const size_t str = (tile < 4) ? xstr : (size_t)H_;
                const int    kof = (tile < 4) ? tile * 256 : tile * 256 - 1024;
                __syncthreads();   // LDS tile safe to overwrite
#pragma unroll
                for (int s4 = 0; s4 < 4; ++s4) {
                    const int e  = (s4 << 9) + tid;    // 0..2047 float4 index
                    const int r  = e >> 6;             // row 0..31
                    const int c4 = (e & 63) << 2;      // col 0..252
                    *(float4*)&xs[r][c4] = *(const float4*)&src[(size_t)r * str + kof + c4];
                }
                __syncthreads();
#pragma unroll
                for (int b = 0; b < 32; ++b) {
                    const float4 a0 = *(const float4*)&xs[b][kb];
                    const float4 a1 = *(const float4*)&xs[b][kb + 4];
                    acc[b] += a0.x * w[tile][0] + a0.y * w[tile][1]
                            + a0.z * w[tile][2] + a0.w * w[tile][3]
                            + a1.x * w[tile][4] + a1.y * w[tile][5]
                            + a1.z * w[tile][6] + a1.w * w[tile][7];
                }
            }

            // ---- two-phase k-reduction through padded LDS (union with xs) ----
            const float* rl = rb + (size_t)layer * B_ * H_;
            float*       wl = wb + (size_t)layer * B_ * H_;
#pragma unroll
            for (int p = 0; p < 2; ++p) {
                __syncthreads();   // previous LDS use complete
#pragma unroll
                for (int c = 0; c < 16; ++c)
                    smem[tid * RP + c] = acc[p * 16 + c];
                __syncthreads();
                if (tid < 256) {
                    const int c = tid >> 4;            // 0..15
                    const int b = c + p * 16;
                    float s = 0.f;
#pragma unroll
                    for (int ks = 0; ks < 32; ++ks)
                        s += smem[(jj + (ks << 4)) * RP + c];
                    const float dx   = tanhf(s + bias);
                    const float hold = rl[(size_t)b * H_ + jg];
                    const float hn   = hold + (dx - hold) / tv;
                    __hip_atomic_store(&wl[(size_t)b * H_ + jg], hn,
                                       __ATOMIC_RELAXED, __HIP_MEMORY_SCOPE_AGENT);
                }
            }
        }

        __syncthreads();   // drain all threads' stores (vmcnt) before release
        if (tid == 0 && !dead)
            __hip_atomic_fetch_add(&count[tick], 1u,
                                   __ATOMIC_RELEASE, __HIP_MEMORY_SCOPE_AGENT);
    }
}

// out[b][o] = sum_k h3[b][k] * W_out[k][o] + b_out[o]   (validated in round 0)
__global__ __launch_bounds__(256) void lnn_out(
    const float* __restrict__ H3,     // [B][H]
    const float* __restrict__ W_out,  // [H][O]
    const float* __restrict__ b_out,  // [O]
    float* __restrict__ out)          // [B][O]
{
    const int gid = blockIdx.x * 256 + threadIdx.x;  // 64 blocks -> 16384 threads
    const int jj  = gid & 1023;
    const int b2  = gid >> 10;                       // 0..15 -> rows b2, b2+16
    float acc0 = b_out[jj];
    float acc1 = b_out[jj];
    for (int k = 0; k < H_; ++k) {
        const float w = W_out[k * H_ + jj];
        acc0 += H3[b2 * H_ + k]        * w;
        acc1 += H3[(b2 + 16) * H_ + k] * w;
    }
    out[b2 * H_ + jj]        = acc0;
    out[(b2 + 16) * H_ + jj] = acc1;
}

extern "C" void kernel_launch(void* const* d_in, const int* in_sizes, int n_in,
                              void* d_out, int out_size, void* d_ws, size_t ws_size,
                              hipStream_t stream) {
    const float* x     = (const float*)d_in[0];
    const float* W_in  = (const float*)d_in[1];
    const float* b_in  = (const float*)d_in[2];
    const float* W_h   = (const float*)d_in[3];
    const float* b_h   = (const float*)d_in[4];
    const float* tau   = (const float*)d_in[5];
    const float* W_out = (const float*)d_in[6];
    const float* b_out = (const float*)d_in[7];

    const size_t stateElems = (size_t)L_ * B_ * H_;       // 131072 floats
    float* buf0 = (float*)d_ws;
    float* buf1 = buf0 + stateElems;
    unsigned int* count = (unsigned int*)(buf1 + stateElems);

    // zero state + lockstep counters (captured in the graph -> reset every replay)
    hipMemsetAsync(d_ws, 0, 2 * stateElems * sizeof(float) + NTICK * sizeof(unsigned int), stream);

    lnn_persist<<<256, 512, 0, stream>>>(x, W_in, b_in, W_h, b_h, tau, buf0, buf1, count);

    // h3 at t=511 computed at tick 514 -> write buffer parity 514&1 = 0 -> buf0
    const float* H3 = buf0 + 3 * (B_ * H_);
    lnn_out<<<64, 256, 0, stream>>>(H3, W_out, b_out, (float*)d_out);
}

// Round 5
// 149176.135 us; speedup vs baseline: 1.0516x; 1.0516x over previous
//
#include <hip/hip_runtime.h>
#include <math.h>

#define B_ 32
#define T_ 512
#define D_ 1024
#define H_ 1024
#define L_ 4
#define NTICK (T_ + L_ - 1)   // 515
#define RP 17                 // reduce-buffer row pad (floats), coprime with 32 banks
#define SMEM_FLOATS (512 * RP) // 8704 floats = 34816 B; aliases staging tile xs[32][256]

// Spin on a RELAXED agent load — no per-poll cache maintenance. The caller
// issues ONE acquire fence after this returns. (Round-2 lesson: per-poll
// ACQUIRE = L2 inv/wb storm = 388 GB of HBM traffic, VALUBusy 3%.)
// Timeout is short (~8 ms) and the caller KEEPS PARTICIPATING in the
// protocol after a timeout, so a straggler degrades to a wrong answer,
// never a hung GPU.
__device__ __forceinline__ bool waitCount(const unsigned int* p, unsigned int target) {
    int c = 0;
    while (__hip_atomic_load(p, __ATOMIC_RELAXED, __HIP_MEMORY_SCOPE_AGENT) < target) {
        __builtin_amdgcn_s_sleep(2);
        if (++c > 100000) return false;   // fail fast; no cascade (see release below)
    }
    return true;
}

// Persistent kernel. 256 blocks (1/CU), 512 threads. Block = (layer, 16-col slice).
// Each thread pins 64 weight floats in VGPRs. Per tick (global lockstep via
// count[tick]): stage x/h k-tiles in LDS, rank-update acc[32 batch rows],
// two-phase LDS k-reduction, tanh + tau update, relaxed-agent store.
__global__ __launch_bounds__(512) void lnn_persist(
    const float* __restrict__ x,      // [B][T][D]
    const float* __restrict__ W_in,   // [L][D][H]
    const float* __restrict__ b_in,   // [L][H]
    const float* __restrict__ W_h,    // [L][H][H]
    const float* __restrict__ b_h,    // [L][H]
    const float* __restrict__ tau,    // [L][H]
    float* __restrict__ buf0,         // [L][B][H] state, tick-parity 0
    float* __restrict__ buf1,         // [L][B][H] state, tick-parity 1
    unsigned int* __restrict__ count) // [NTICK] lockstep counters (zeroed per launch)
{
    const int tid   = threadIdx.x;
    const int layer = blockIdx.x >> 6;
    const int jbase = (blockIdx.x & 63) << 4;
    const int jj    = tid & 15;       // col within slice
    const int kslot = tid >> 4;       // 0..31
    const int jg    = jbase + jj;

    __shared__ __align__(16) float smem[SMEM_FLOATS];
    float (*xs)[256] = (float(*)[256])smem;

    // ---- pin weights in registers (64 floats/thread), loaded once ----
    const float* Wl_in = W_in + (size_t)layer * D_ * H_;
    const float* Wl_h  = W_h  + (size_t)layer * H_ * H_;
    float w[8][8];
#pragma unroll
    for (int tl = 0; tl < 8; ++tl) {
#pragma unroll
        for (int i = 0; i < 8; ++i) {
            const int k = tl * 256 + kslot * 8 + i;
            w[tl][i] = (tl < 4) ? Wl_in[(size_t)k * H_ + jg]
                                : Wl_h[(size_t)(k - 1024) * H_ + jg];
        }
    }

    const float bias = b_in[layer * H_ + jg] + b_h[layer * H_ + jg];
    const float tv   = tau[layer * H_ + jg];

    for (int tick = 0; tick < NTICK; ++tick) {
        if (tid == 0 && tick > 0) {
            (void)waitCount(&count[tick - 1], 256u);
            // ONE acquire per tick per block: invalidate stale caches so the
            // staging loads below see other blocks' tick-1 stores.
            __builtin_amdgcn_fence(__ATOMIC_ACQUIRE, "agent");
        }
        __syncthreads();   // all threads ordered after the acquire

        const int t = tick - layer;
        if (t >= 0 && t < T_) {
            const float* rb = (tick & 1) ? buf0 : buf1;   // state at t-1
            float*       wb = (tick & 1) ? buf1 : buf0;   // state at t

            const float* xsrc; size_t xstr;
            if (layer == 0) { xsrc = x + (size_t)t * D_;               xstr = (size_t)T_ * D_; }
            else            { xsrc = rb + (size_t)(layer - 1) * B_ * H_; xstr = H_; }
            const float* hsrc = rb + (size_t)layer * B_ * H_;

            float acc[32];
#pragma unroll
            for (int i = 0; i < 32; ++i) acc[i] = 0.f;

            const int kb = kslot << 3;
#pragma unroll
            for (int tile = 0; tile < 8; ++tile) {
                const float* src = (tile < 4) ? xsrc : hsrc;
                const size_t str = (tile < 4) ? xstr : (size_t)H_;
                const int    kof = (tile < 4) ? tile * 256 : tile * 256 - 1024;
                __syncthreads();   // LDS tile safe to overwrite
#pragma unroll
                for (int s4 = 0; s4 < 4; ++s4) {
                    const int e  = (s4 << 9) + tid;    // 0..2047 float4 index
                    const int r  = e >> 6;             // row 0..31
                    const int c4 = (e & 63) << 2;      // col 0..252
                    *(float4*)&xs[r][c4] = *(const float4*)&src[(size_t)r * str + kof + c4];
                }
                __syncthreads();
#pragma unroll
                for (int b = 0; b < 32; ++b) {
                    const float4 a0 = *(const float4*)&xs[b][kb];
                    const float4 a1 = *(const float4*)&xs[b][kb + 4];
                    acc[b] += a0.x * w[tile][0] + a0.y * w[tile][1]
                            + a0.z * w[tile][2] + a0.w * w[tile][3]
                            + a1.x * w[tile][4] + a1.y * w[tile][5]
                            + a1.z * w[tile][6] + a1.w * w[tile][7];
                }
            }

            // ---- two-phase k-reduction through padded LDS (union with xs) ----
            const float* rl = rb + (size_t)layer * B_ * H_;
            float*       wl = wb + (size_t)layer * B_ * H_;
#pragma unroll
            for (int p = 0; p < 2; ++p) {
                __syncthreads();   // previous LDS use complete
#pragma unroll
                for (int c = 0; c < 16; ++c)
                    smem[tid * RP + c] = acc[p * 16 + c];
                __syncthreads();
                if (tid < 256) {
                    const int c = tid >> 4;            // 0..15
                    const int b = c + p * 16;
                    float s = 0.f;
#pragma unroll
                    for (int ks = 0; ks < 32; ++ks)
                        s += smem[(jj + (ks << 4)) * RP + c];
                    const float dx   = tanhf(s + bias);
                    const float hold = rl[(size_t)b * H_ + jg];
                    const float hn   = hold + (dx - hold) / tv;
                    // relaxed agent store: lands at the coherence point, so the
                    // release-add below publishes it without extra flushing.
                    __hip_atomic_store(&wl[(size_t)b * H_ + jg], hn,
                                       __ATOMIC_RELAXED, __HIP_MEMORY_SCOPE_AGENT);
                }
            }
        }

        __syncthreads();   // all waves' stores issued & drained before release
        // ALWAYS increment — even after a wait timeout. A straggler must not
        // starve the other 255 blocks into per-tick timeouts (hang-by-cascade).
        if (tid == 0)
            __hip_atomic_fetch_add(&count[tick], 1u,
                                   __ATOMIC_RELEASE, __HIP_MEMORY_SCOPE_AGENT);
    }
}

// out[b][o] = sum_k h3[b][k] * W_out[k][o] + b_out[o]   (validated in round 0)
__global__ __launch_bounds__(256) void lnn_out(
    const float* __restrict__ H3,     // [B][H]
    const float* __restrict__ W_out,  // [H][O]
    const float* __restrict__ b_out,  // [O]
    float* __restrict__ out)          // [B][O]
{
    const int gid = blockIdx.x * 256 + threadIdx.x;  // 64 blocks -> 16384 threads
    const int jj  = gid & 1023;
    const int b2  = gid >> 10;                       // 0..15 -> rows b2, b2+16
    float acc0 = b_out[jj];
    float acc1 = b_out[jj];
    for (int k = 0; k < H_; ++k) {
        const float w = W_out[k * H_ + jj];
        acc0 += H3[b2 * H_ + k]        * w;
        acc1 += H3[(b2 + 16) * H_ + k] * w;
    }
    out[b2 * H_ + jj]        = acc0;
    out[(b2 + 16) * H_ + jj] = acc1;
}

extern "C" void kernel_launch(void* const* d_in, const int* in_sizes, int n_in,
                              void* d_out, int out_size, void* d_ws, size_t ws_size,
                              hipStream_t stream) {
    const float* x     = (const float*)d_in[0];
    const float* W_in  = (const float*)d_in[1];
    const float* b_in  = (const float*)d_in[2];
    const float* W_h   = (const float*)d_in[3];
    const float* b_h   = (const float*)d_in[4];
    const float* tau   = (const float*)d_in[5];
    const float* W_out = (const float*)d_in[6];
    const float* b_out = (const float*)d_in[7];

    const size_t stateElems = (size_t)L_ * B_ * H_;       // 131072 floats
    float* buf0 = (float*)d_ws;
    float* buf1 = buf0 + stateElems;
    unsigned int* count = (unsigned int*)(buf1 + stateElems);

    // zero state + lockstep counters (captured in the graph -> reset every replay)
    (void)hipMemsetAsync(d_ws, 0, 2 * stateElems * sizeof(float) + NTICK * sizeof(unsigned int), stream);

    lnn_persist<<<256, 512, 0, stream>>>(x, W_in, b_in, W_h, b_h, tau, buf0, buf1, count);

    // h3 at t=511 computed at tick 514 -> write buffer parity 514&1 = 0 -> buf0
    const float* H3 = buf0 + 3 * (B_ * H_);
    lnn_out<<<64, 256, 0, stream>>>(H3, W_out, b_out, (float*)d_out);
}